// Round 5
// baseline (1937.673 us; speedup 1.0000x reference)
//
#include <hip/hip_runtime.h>

#define HH 256
#define WW 512
#define CPG 144
#define NKG 18                         // 144 ch = 18 groups of 8
#define WP 516                         // 512 + 2 left + 2 right
#define HPADR 258                      // 256 + 2 top halo rows
#define XB_E ((size_t)NKG * HPADR * WP * 8)   // 19170432 elems per activation buffer
#define NCH 59                         // K-chunks of 32 (K = 13*144 = 1872)
#define KREAL 1872
#define SCALE_F (2.0f / 47.0f)

typedef __attribute__((ext_vector_type(8))) short short8;
typedef __attribute__((ext_vector_type(4))) float floatx4;

__device__ __forceinline__ unsigned short f2bf(float f) {
    unsigned u = __builtin_bit_cast(unsigned, f);
    u += 0x7FFFu + ((u >> 16) & 1u);
    return (unsigned short)(u >> 16);
}
__device__ __forceinline__ float bf2f(unsigned short h) {
    unsigned u = ((unsigned)h) << 16;
    return __builtin_bit_cast(float, u);
}
// mask-B taps t=0..12: kh = t<5?0:(t<10?1:2), kw = t - {0,5,10}
__device__ __forceinline__ void tap_decode(int t, int& kh, int& kw) {
    kh = t < 5 ? 0 : (t < 10 ? 1 : 2);
    kw = t - (t < 5 ? 0 : (t < 10 ? 5 : 10));
}

// ---------------- zero workspace ------------------------------------------
__global__ void k_zero(float* __restrict__ p, size_t n4) {
    size_t i = (size_t)blockIdx.x * blockDim.x + threadIdx.x;
    size_t stride = (size_t)gridDim.x * blockDim.x;
    float4 z = make_float4(0.f, 0.f, 0.f, 0.f);
    for (; i < n4; i += stride) ((float4*)p)[i] = z;
}

// ---------------- weight packing (linear-K layout) ------------------------
// hidden: wpk[l][c][co144][kk32], K = c*32+kk -> (t = K/144, ci = K%144)
__global__ void k_pack_hidden(const float* __restrict__ wres, unsigned short* __restrict__ wpk) {
    const int total = 10 * NCH * CPG * 32;
    int i = blockIdx.x * blockDim.x + threadIdx.x;
    int stride = gridDim.x * blockDim.x;
    for (; i < total; i += stride) {
        int kk = i & 31;
        int q  = i >> 5;
        int co = q % CPG;
        int c  = (q / CPG) % NCH;
        int l  = q / (CPG * NCH);
        int K = c * 32 + kk;
        float v = 0.f;
        if (K < KREAL) {
            int t = K / CPG, ci = K - t * CPG;
            int kh, kw; tap_decode(t, kh, kw);
            v = wres[(((size_t)(l * CPG + co) * CPG + ci) * 5 + kh) * 5 + kw];
        }
        wpk[i] = f2bf(v);
    }
}
// final: wpkF[c][co64][kk32] (co>=49 zero)
__global__ void k_pack_final(const float* __restrict__ wl, unsigned short* __restrict__ wpkF) {
    const int total = NCH * 64 * 32;
    int i = blockIdx.x * blockDim.x + threadIdx.x;
    if (i >= total) return;
    int kk = i & 31;
    int co = (i >> 5) & 63;
    int c  = i >> 11;
    int K = c * 32 + kk;
    float v = 0.f;
    if (K < KREAL && co < 49) {
        int t = K / CPG, ci = K - t * CPG;
        int kh, kw; tap_decode(t, kh, kw);
        v = wl[(((size_t)co * CPG + ci) * 5 + kh) * 5 + kw];
    }
    wpkF[i] = f2bf(v);
}
// small: w0p[t*144+co] fp32 (12 mask-A taps) + blp[64] (bias pad)
__global__ void k_pack_small(const float* __restrict__ w0, const float* __restrict__ bl,
                             float* __restrict__ w0p, float* __restrict__ blp) {
    int i = blockIdx.x * blockDim.x + threadIdx.x;
    if (i < 12 * CPG) {
        int co = i % CPG, t = i / CPG;
        int kh, kw; tap_decode(t, kh, kw);   // t<12: mask-A (row2 only kw 0,1)
        w0p[i] = w0[co * 25 + kh * 5 + kw];
    } else if (i < 12 * CPG + 64) {
        int k = i - 12 * CPG;
        blp[k] = k < 49 ? bl[k] : 0.f;
    }
}

// ---------------- layer 0: data -> Xb bf16 blocked [kg][y][x][8] ----------
__global__ __launch_bounds__(384) void k_layer0(
    const float* __restrict__ data, const float* __restrict__ w0p,
    const float* __restrict__ b0, unsigned short* __restrict__ Xb) {
    const int lane = threadIdx.x;                 // 0..63
    const int x = blockIdx.x * 64 + lane;
    const int y = blockIdx.y;

    float xv[12];
#pragma unroll
    for (int t = 0; t < 12; t++) {
        int kh, kw; tap_decode(t, kh, kw);
        int yy = y + kh - 2, xx = x + kw - 2;
        xv[t] = (yy >= 0 && xx >= 0 && xx < WW) ? data[yy * WW + xx] * SCALE_F - 1.0f : 0.f;
    }
#pragma unroll
    for (int kgi = 0; kgi < 3; kgi++) {
        int kg = threadIdx.y * 3 + kgi;           // 0..17
        float a8[8];
#pragma unroll
        for (int j = 0; j < 8; j++) a8[j] = 0.f;
#pragma unroll
        for (int t = 0; t < 12; t++)
#pragma unroll
            for (int j = 0; j < 8; j++)
                a8[j] = fmaf(w0p[t * CPG + kg * 8 + j], xv[t], a8[j]);
        short8 o;
#pragma unroll
        for (int j = 0; j < 8; j++)
            o[j] = (short)f2bf(fmaxf(a8[j] + b0[kg * 8 + j], 0.f));
        *(short8*)&Xb[((size_t)(kg * HPADR + y + 2) * WP + (x + 2)) * 8] = o;
    }
}

// ---------------- hidden conv: direct-load implicit GEMM (no LDS) ---------
// block = 3 waves = one 128px tile x 3 co-groups of 48. Wave: Mf=8, Nf=3.
// A-frag = one coalesced global_load_dwordx4 per wave (lane=px, 256B/16-lane).
// No barriers: waves fully independent, compiler pipelines loads over MFMAs.
template<bool RES>
__global__ __launch_bounds__(192, 2) void k_conv(
    const unsigned short* __restrict__ in,
    const unsigned short* __restrict__ wq,
    const float* __restrict__ bias,
    const unsigned short* __restrict__ res,
    unsigned short* __restrict__ out) {
    const int lane = threadIdx.x & 63;
    const int ng   = threadIdx.x >> 6;   // 0..2
    const int lr = lane & 15;
    const int lg = lane >> 4;
    const int y  = blockIdx.y;
    const int x0 = blockIdx.x * 128;

    floatx4 acc[8][3];
#pragma unroll
    for (int m = 0; m < 8; m++)
#pragma unroll
        for (int n = 0; n < 3; n++) acc[m][n] = (floatx4)0.f;

#pragma unroll 1
    for (int c = 0; c < NCH; ++c) {
        // per-lane A address (lg picks this lane's 8-channel group of the chunk)
        int g = c * 4 + lg;                  // 8-ch group index
        if (g > 233) g = 233;                // pad K: weights are 0 there
        int t = (g * 57) >> 10;              // g/18, exact for g<=233
        int kgp = g - t * 18;                // which 8-ch plane
        int kh, kw; tap_decode(t, kh, kw);
        const unsigned short* ap =
            in + ((size_t)(kgp * HPADR + y + kh) * WP + (x0 + kw + lr)) * 8;
        const unsigned short* bp =
            wq + ((size_t)c * CPG + ng * 48 + lr) * 32 + lg * 8;
        short8 a[8], b[3];
#pragma unroll
        for (int m = 0; m < 8; ++m) a[m] = *(const short8*)(ap + m * 128);
#pragma unroll
        for (int n = 0; n < 3; ++n) b[n] = *(const short8*)(bp + n * 512);
#pragma unroll
        for (int m = 0; m < 8; ++m)
#pragma unroll
            for (int n = 0; n < 3; ++n)
                acc[m][n] = __builtin_amdgcn_mfma_f32_16x16x32_bf16(
                    a[m], b[n], acc[m][n], 0, 0, 0);
    }

#pragma unroll
    for (int n = 0; n < 3; ++n) {
        int co = ng * 48 + n * 16 + lr;
        float bv = bias[co];
        const size_t pb = ((size_t)((co >> 3) * HPADR + y + 2) * WP + (x0 + 2)) * 8 + (co & 7);
#pragma unroll
        for (int m = 0; m < 8; ++m)
#pragma unroll
            for (int r = 0; r < 4; ++r) {
                int px = m * 16 + lg * 4 + r;
                size_t o = pb + (size_t)px * 8;
                float v = fmaxf(acc[m][n][r] + bv, 0.f);
                if (RES) v += bf2f(res[o]);
                out[o] = f2bf(v);
            }
    }
}

// ---------------- final conv (144 -> 49 pad 64) -> fp32 logits ------------
// 4 independent waves per block, each: 128px x 64co (Mf=8, Nf=4).
__global__ __launch_bounds__(256, 2) void k_logits(
    const unsigned short* __restrict__ in,
    const unsigned short* __restrict__ wq,
    const float* __restrict__ blp,
    float* __restrict__ logits) {
    const int lane = threadIdx.x & 63;
    const int wid  = threadIdx.x >> 6;   // 0..3
    const int lr = lane & 15;
    const int lg = lane >> 4;
    const int tt = blockIdx.x * 4 + wid; // px-tile id 0..1023
    const int y  = tt >> 2;
    const int x0 = (tt & 3) * 128;

    floatx4 acc[8][4];
#pragma unroll
    for (int m = 0; m < 8; m++)
#pragma unroll
        for (int n = 0; n < 4; n++) acc[m][n] = (floatx4)0.f;

#pragma unroll 1
    for (int c = 0; c < NCH; ++c) {
        int g = c * 4 + lg;
        if (g > 233) g = 233;
        int t = (g * 57) >> 10;
        int kgp = g - t * 18;
        int kh, kw; tap_decode(t, kh, kw);
        const unsigned short* ap =
            in + ((size_t)(kgp * HPADR + y + kh) * WP + (x0 + kw + lr)) * 8;
        const unsigned short* bp =
            wq + ((size_t)c * 64 + lr) * 32 + lg * 8;
        short8 a[8], b[4];
#pragma unroll
        for (int m = 0; m < 8; ++m) a[m] = *(const short8*)(ap + m * 128);
#pragma unroll
        for (int n = 0; n < 4; ++n) b[n] = *(const short8*)(bp + n * 512);
#pragma unroll
        for (int m = 0; m < 8; ++m)
#pragma unroll
            for (int n = 0; n < 4; ++n)
                acc[m][n] = __builtin_amdgcn_mfma_f32_16x16x32_bf16(
                    a[m], b[n], acc[m][n], 0, 0, 0);
    }

#pragma unroll
    for (int n = 0; n < 4; ++n) {
        int co = n * 16 + lr;
        float bv = blp[co];
#pragma unroll
        for (int m = 0; m < 8; ++m)
#pragma unroll
            for (int r = 0; r < 4; ++r) {
                int px = m * 16 + lg * 4 + r;
                logits[((size_t)y * WW + x0 + px) * 64 + co] = acc[m][n][r] + bv;
            }
    }
}

// ---------------- softmax + cdf -> d_out ----------------------------------
__global__ __launch_bounds__(256) void k_softmax(
    const float* __restrict__ lg, float* __restrict__ out) {
    const int px = blockIdx.x * 256 + threadIdx.x;
    const int y = blockIdx.y;
    const size_t p = (size_t)y * WW + px;
    const float* l = lg + p * 64;
    float v[49];
    float m = -1e30f;
#pragma unroll
    for (int k = 0; k < 49; k++) { v[k] = l[k]; m = fmaxf(m, v[k]); }
    float s = 0.f;
#pragma unroll
    for (int k = 0; k < 49; k++) {
        v[k] = exp2f((v[k] - m) * 1.44269504088896f);
        s += v[k];
    }
    const float inv = 65536.0f / s;
    out[p] = 0.f;
    float run = 0.f;
#pragma unroll
    for (int k = 0; k < 49; k++) {
        run += v[k];
        out[(size_t)(k + 1) * (HH * WW) + p] = run * inv;
    }
}

// ---------------- launcher -------------------------------------------------
extern "C" void kernel_launch(void* const* d_in, const int* in_sizes, int n_in,
                              void* d_out, int out_size, void* d_ws, size_t ws_size,
                              hipStream_t stream) {
    (void)in_sizes; (void)n_in; (void)out_size; (void)ws_size;
    const float* data = (const float*)d_in[0];
    const float* w0   = (const float*)d_in[1];
    const float* b0   = (const float*)d_in[2];
    const float* wres = (const float*)d_in[3];
    const float* bres = (const float*)d_in[4];
    const float* wl   = (const float*)d_in[5];
    const float* bl   = (const float*)d_in[6];
    float* out = (float*)d_out;

    char* ws = (char*)d_ws;
    unsigned short* Xb   = (unsigned short*)ws;                 // 19170432 elems
    unsigned short* Hb   = Xb + XB_E;                           // 19170432
    unsigned short* wpk  = Hb + XB_E;                           // 10*59*144*32 = 2718720
    unsigned short* wpkF = wpk + (size_t)10 * NCH * CPG * 32;   // 59*64*32 = 120832
    float* blp  = (float*)(wpkF + (size_t)NCH * 64 * 32);       // 64
    float* w0p  = blp + 64;                                     // 1728
    float* logits = w0p + 1728;                                 // 131072*64 fp32

    // zero both activation buffers (halos must be 0; ws is poisoned)
    k_zero<<<2048, 256, 0, stream>>>((float*)ws, (2 * XB_E * 2) / 16);

    k_pack_hidden<<<2048, 256, 0, stream>>>(wres, wpk);
    k_pack_final<<<(NCH * 64 * 32 + 255) / 256, 256, 0, stream>>>(wl, wpkF);
    k_pack_small<<<7, 256, 0, stream>>>(w0, bl, w0p, blp);

    k_layer0<<<dim3(8, 256), dim3(64, 6), 0, stream>>>(data, w0p, b0, Xb);

    const size_t LSTRIDE = (size_t)NCH * CPG * 32;   // 271872
    for (int i = 0; i < 5; i++) {
        k_conv<false><<<dim3(4, 256), 192, 0, stream>>>(
            Xb, wpk + (size_t)(2 * i) * LSTRIDE, bres + (2 * i) * CPG, Xb, Hb);
        k_conv<true><<<dim3(4, 256), 192, 0, stream>>>(
            Hb, wpk + (size_t)(2 * i + 1) * LSTRIDE, bres + (2 * i + 1) * CPG, Xb, Xb);
    }

    k_logits<<<256, 256, 0, stream>>>(Xb, wpkF, blp, logits);
    k_softmax<<<dim3(2, 256), 256, 0, stream>>>(logits, out);
}

// Round 6
// 1904.441 us; speedup vs baseline: 1.0174x; 1.0174x over previous
//
#include <hip/hip_runtime.h>

#define HH 256
#define WW 512
#define CPG 144
#define NKG 18                         // 144 ch = 18 groups of 8
#define WP 516                         // 512 + 2 left + 2 right
#define HPADR 258                      // 256 + 2 top halo rows
#define XB_E ((size_t)NKG * HPADR * WP * 8)   // 19170432 elems per activation buffer
#define NCH 59                         // K-chunks of 32 (K = 13*144 = 1872)
#define KREAL 1872
#define SCALE_F (2.0f / 47.0f)

typedef __attribute__((ext_vector_type(8))) short short8;
typedef __attribute__((ext_vector_type(4))) float floatx4;

__device__ __forceinline__ unsigned short f2bf(float f) {
    unsigned u = __builtin_bit_cast(unsigned, f);
    u += 0x7FFFu + ((u >> 16) & 1u);
    return (unsigned short)(u >> 16);
}
__device__ __forceinline__ float bf2f(unsigned short h) {
    unsigned u = ((unsigned)h) << 16;
    return __builtin_bit_cast(float, u);
}
__device__ __forceinline__ void async16(const void* g, void* l) {
    __builtin_amdgcn_global_load_lds(
        (const __attribute__((address_space(1))) unsigned int*)g,
        (__attribute__((address_space(3))) unsigned int*)l, 16, 0, 0);
}
// mask-B taps t=0..12: kh = t<5?0:(t<10?1:2), kw = t - {0,5,10}
__device__ __forceinline__ void tap_decode(int t, int& kh, int& kw) {
    kh = t < 5 ? 0 : (t < 10 ? 1 : 2);
    kw = t - (t < 5 ? 0 : (t < 10 ? 5 : 10));
}

// ---------------- zero workspace ------------------------------------------
__global__ void k_zero(float* __restrict__ p, size_t n4) {
    size_t i = (size_t)blockIdx.x * blockDim.x + threadIdx.x;
    size_t stride = (size_t)gridDim.x * blockDim.x;
    float4 z = make_float4(0.f, 0.f, 0.f, 0.f);
    for (; i < n4; i += stride) ((float4*)p)[i] = z;
}

// ---------------- weight packing (linear-K layout) ------------------------
// hidden: wpk[l][c][co144][kk32], K = c*32+kk -> (t = K/144, ci = K%144)
__global__ void k_pack_hidden(const float* __restrict__ wres, unsigned short* __restrict__ wpk) {
    const int total = 10 * NCH * CPG * 32;
    int i = blockIdx.x * blockDim.x + threadIdx.x;
    int stride = gridDim.x * blockDim.x;
    for (; i < total; i += stride) {
        int kk = i & 31;
        int q  = i >> 5;
        int co = q % CPG;
        int c  = (q / CPG) % NCH;
        int l  = q / (CPG * NCH);
        int K = c * 32 + kk;
        float v = 0.f;
        if (K < KREAL) {
            int t = K / CPG, ci = K - t * CPG;
            int kh, kw; tap_decode(t, kh, kw);
            v = wres[(((size_t)(l * CPG + co) * CPG + ci) * 5 + kh) * 5 + kw];
        }
        wpk[i] = f2bf(v);
    }
}
// final: wpkF[c][co64][kk32] (co>=49 zero)
__global__ void k_pack_final(const float* __restrict__ wl, unsigned short* __restrict__ wpkF) {
    const int total = NCH * 64 * 32;
    int i = blockIdx.x * blockDim.x + threadIdx.x;
    if (i >= total) return;
    int kk = i & 31;
    int co = (i >> 5) & 63;
    int c  = i >> 11;
    int K = c * 32 + kk;
    float v = 0.f;
    if (K < KREAL && co < 49) {
        int t = K / CPG, ci = K - t * CPG;
        int kh, kw; tap_decode(t, kh, kw);
        v = wl[(((size_t)co * CPG + ci) * 5 + kh) * 5 + kw];
    }
    wpkF[i] = f2bf(v);
}
// small: w0p[t*144+co] fp32 (12 mask-A taps) + blp[64] (bias pad)
__global__ void k_pack_small(const float* __restrict__ w0, const float* __restrict__ bl,
                             float* __restrict__ w0p, float* __restrict__ blp) {
    int i = blockIdx.x * blockDim.x + threadIdx.x;
    if (i < 12 * CPG) {
        int co = i % CPG, t = i / CPG;
        int kh, kw; tap_decode(t, kh, kw);   // t<12: mask-A (row2 only kw 0,1)
        w0p[i] = w0[co * 25 + kh * 5 + kw];
    } else if (i < 12 * CPG + 64) {
        int k = i - 12 * CPG;
        blp[k] = k < 49 ? bl[k] : 0.f;
    }
}

// ---------------- layer 0: data -> Xb bf16 blocked [kg][y][x][8] ----------
__global__ __launch_bounds__(384) void k_layer0(
    const float* __restrict__ data, const float* __restrict__ w0p,
    const float* __restrict__ b0, unsigned short* __restrict__ Xb) {
    const int lane = threadIdx.x;                 // 0..63
    const int x = blockIdx.x * 64 + lane;
    const int y = blockIdx.y;

    float xv[12];
#pragma unroll
    for (int t = 0; t < 12; t++) {
        int kh, kw; tap_decode(t, kh, kw);
        int yy = y + kh - 2, xx = x + kw - 2;
        xv[t] = (yy >= 0 && xx >= 0 && xx < WW) ? data[yy * WW + xx] * SCALE_F - 1.0f : 0.f;
    }
#pragma unroll
    for (int kgi = 0; kgi < 3; kgi++) {
        int kg = threadIdx.y * 3 + kgi;           // 0..17
        float a8[8];
#pragma unroll
        for (int j = 0; j < 8; j++) a8[j] = 0.f;
#pragma unroll
        for (int t = 0; t < 12; t++)
#pragma unroll
            for (int j = 0; j < 8; j++)
                a8[j] = fmaf(w0p[t * CPG + kg * 8 + j], xv[t], a8[j]);
        short8 o;
#pragma unroll
        for (int j = 0; j < 8; j++)
            o[j] = (short)f2bf(fmaxf(a8[j] + b0[kg * 8 + j], 0.f));
        *(short8*)&Xb[((size_t)(kg * HPADR + y + 2) * WP + (x + 2)) * 8] = o;
    }
}

// ---------------- hidden conv: stage-once LDS implicit GEMM ---------------
// block = 128px x 2 output rows x all 144 co; 8 waves = (row 0..1) x (px-quarter 0..3).
// LDS: full 4-row x 132-px x 144-ch window (152 KB) staged ONCE; K-loop has
// no barriers, no re-staging. Wave tile: Mf=2 (32px) x Nf=9 (144co) ->
// 18 MFMA per 2 ds_read_b128 (LDS ~= MFMA balance). B from global (L1-hot).
template<bool RES>
__global__ __launch_bounds__(512, 2) void k_conv(
    const unsigned short* __restrict__ in,
    const unsigned short* __restrict__ wq,
    const float* __restrict__ bias,
    const unsigned short* __restrict__ res,
    unsigned short* __restrict__ out) {
    __shared__ __align__(16) unsigned short As[NKG][4][132][8];   // 152064 B
    const int tid  = threadIdx.x;
    const int lane = tid & 63;
    const int wid  = tid >> 6;          // 0..7
    const int r    = wid >> 2;          // output row 0..1
    const int mq   = wid & 3;           // px quarter (32 px)
    const int lr = lane & 15;
    const int lg = lane >> 4;

    // XCD-chunked swizzle: 512 blocks -> 64 consecutive per XCD (y-band locality)
    const int fid = blockIdx.x + (int)gridDim.x * blockIdx.y;   // 0..511
    const int swz = (fid & 7) * 64 + (fid >> 3);
    const int x0 = (swz & 3) * 128;     // padded-col base of staged window
    const int y0 = (swz >> 2) * 2;      // padded-row base of staged window

    floatx4 acc[2][9];
#pragma unroll
    for (int m = 0; m < 2; m++)
#pragma unroll
        for (int n = 0; n < 9; n++) acc[m][n] = (floatx4)0.f;

    // ---- staging ----
    auto stage_rows = [&](int r0) {     // rows r0, r0+1, px 0..127 via gll
        for (int i = wid; i < 72; i += 8) {
            int kg = i >> 2;
            int rr = r0 + ((i >> 1) & 1);
            int half = i & 1;
            async16(in + ((size_t)(kg * HPADR + y0 + rr) * WP + x0 + half * 64 + lane) * 8,
                    &As[kg][rr][half * 64][0]);
        }
    };
    stage_rows(0);
    if (tid < 288) {                    // halo px 128..131, all 4 rows
        int kg = tid >> 4;
        int rr = (tid >> 2) & 3;
        int pxl = 128 + (tid & 3);
        *(short8*)&As[kg][rr][pxl][0] =
            *(const short8*)(in + ((size_t)(kg * HPADR + y0 + rr) * WP + x0 + pxl) * 8);
    }
    asm volatile("s_waitcnt vmcnt(0) lgkmcnt(0)" ::: "memory");
    __builtin_amdgcn_s_barrier();
    __builtin_amdgcn_sched_barrier(0);
    stage_rows(2);                      // rows 2,3 in flight under kh=0 chunks

    // ---- K-loop (no barriers inside a phase) ----
    auto compute = [&](int c0, int c1) {
#pragma unroll 2
        for (int c = c0; c < c1; ++c) {
            int g = c * 4 + lg;              // per-lane 8-ch group
            if (g > 233) g = 233;            // pad K: weights are 0 there
            int t = (g * 57) >> 10;          // g/18, exact for g<=233
            int kgp = g - t * 18;
            int kh, kw; tap_decode(t, kh, kw);
            const unsigned short* ap = &As[kgp][r + kh][mq * 32 + kw + lr][0];
            short8 a0 = *(const short8*)ap;
            short8 a1 = *(const short8*)(ap + 16 * 8);
            const unsigned short* bp = wq + (size_t)c * 4608 + lr * 32 + lg * 8;
            short8 b[9];
#pragma unroll
            for (int n = 0; n < 9; ++n) b[n] = *(const short8*)(bp + n * 512);
#pragma unroll
            for (int n = 0; n < 9; ++n) {
                acc[0][n] = __builtin_amdgcn_mfma_f32_16x16x32_bf16(a0, b[n], acc[0][n], 0, 0, 0);
                acc[1][n] = __builtin_amdgcn_mfma_f32_16x16x32_bf16(a1, b[n], acc[1][n], 0, 0, 0);
            }
        }
    };
    compute(0, 22);                      // t<=4 -> kh=0 -> rows 0,1 only
    asm volatile("s_waitcnt vmcnt(0)" ::: "memory");
    __builtin_amdgcn_s_barrier();
    __builtin_amdgcn_sched_barrier(0);
    compute(22, NCH);

    // ---- epilogue ----
#pragma unroll
    for (int n = 0; n < 9; ++n) {
        int co = n * 16 + lr;
        float bv = bias[co];
        const size_t pb = ((size_t)((co >> 3) * HPADR + y0 + 2 + r) * WP + (x0 + 2)) * 8 + (co & 7);
#pragma unroll
        for (int m = 0; m < 2; ++m)
#pragma unroll
            for (int rr = 0; rr < 4; ++rr) {
                int px = mq * 32 + m * 16 + lg * 4 + rr;
                size_t o = pb + (size_t)px * 8;
                float v = fmaxf(acc[m][n][rr] + bv, 0.f);
                if (RES) v += bf2f(res[o]);
                out[o] = f2bf(v);
            }
    }
}

// ---------------- final conv (144 -> 49 pad 64) -> fp32 logits ------------
// 4 independent waves per block, each: 128px x 64co (Mf=8, Nf=4).
__global__ __launch_bounds__(256, 2) void k_logits(
    const unsigned short* __restrict__ in,
    const unsigned short* __restrict__ wq,
    const float* __restrict__ blp,
    float* __restrict__ logits) {
    const int lane = threadIdx.x & 63;
    const int wid  = threadIdx.x >> 6;   // 0..3
    const int lr = lane & 15;
    const int lg = lane >> 4;
    const int tt = blockIdx.x * 4 + wid; // px-tile id 0..1023
    const int y  = tt >> 2;
    const int x0 = (tt & 3) * 128;

    floatx4 acc[8][4];
#pragma unroll
    for (int m = 0; m < 8; m++)
#pragma unroll
        for (int n = 0; n < 4; n++) acc[m][n] = (floatx4)0.f;

#pragma unroll 1
    for (int c = 0; c < NCH; ++c) {
        int g = c * 4 + lg;
        if (g > 233) g = 233;
        int t = (g * 57) >> 10;
        int kgp = g - t * 18;
        int kh, kw; tap_decode(t, kh, kw);
        const unsigned short* ap =
            in + ((size_t)(kgp * HPADR + y + kh) * WP + (x0 + kw + lr)) * 8;
        const unsigned short* bp =
            wq + ((size_t)c * 64 + lr) * 32 + lg * 8;
        short8 a[8], b[4];
#pragma unroll
        for (int m = 0; m < 8; ++m) a[m] = *(const short8*)(ap + m * 128);
#pragma unroll
        for (int n = 0; n < 4; ++n) b[n] = *(const short8*)(bp + n * 512);
#pragma unroll
        for (int m = 0; m < 8; ++m)
#pragma unroll
            for (int n = 0; n < 4; ++n)
                acc[m][n] = __builtin_amdgcn_mfma_f32_16x16x32_bf16(
                    a[m], b[n], acc[m][n], 0, 0, 0);
    }

#pragma unroll
    for (int n = 0; n < 4; ++n) {
        int co = n * 16 + lr;
        float bv = blp[co];
#pragma unroll
        for (int m = 0; m < 8; ++m)
#pragma unroll
            for (int rr = 0; rr < 4; ++rr) {
                int px = m * 16 + lg * 4 + rr;
                logits[((size_t)y * WW + x0 + px) * 64 + co] = acc[m][n][rr] + bv;
            }
    }
}

// ---------------- softmax + cdf -> d_out ----------------------------------
__global__ __launch_bounds__(256) void k_softmax(
    const float* __restrict__ lg, float* __restrict__ out) {
    const int px = blockIdx.x * 256 + threadIdx.x;
    const int y = blockIdx.y;
    const size_t p = (size_t)y * WW + px;
    const float* l = lg + p * 64;
    float v[49];
    float m = -1e30f;
#pragma unroll
    for (int k = 0; k < 49; k++) { v[k] = l[k]; m = fmaxf(m, v[k]); }
    float s = 0.f;
#pragma unroll
    for (int k = 0; k < 49; k++) {
        v[k] = exp2f((v[k] - m) * 1.44269504088896f);
        s += v[k];
    }
    const float inv = 65536.0f / s;
    out[p] = 0.f;
    float run = 0.f;
#pragma unroll
    for (int k = 0; k < 49; k++) {
        run += v[k];
        out[(size_t)(k + 1) * (HH * WW) + p] = run * inv;
    }
}

// ---------------- launcher -------------------------------------------------
extern "C" void kernel_launch(void* const* d_in, const int* in_sizes, int n_in,
                              void* d_out, int out_size, void* d_ws, size_t ws_size,
                              hipStream_t stream) {
    (void)in_sizes; (void)n_in; (void)out_size; (void)ws_size;
    const float* data = (const float*)d_in[0];
    const float* w0   = (const float*)d_in[1];
    const float* b0   = (const float*)d_in[2];
    const float* wres = (const float*)d_in[3];
    const float* bres = (const float*)d_in[4];
    const float* wl   = (const float*)d_in[5];
    const float* bl   = (const float*)d_in[6];
    float* out = (float*)d_out;

    char* ws = (char*)d_ws;
    unsigned short* Xb   = (unsigned short*)ws;                 // 19170432 elems
    unsigned short* Hb   = Xb + XB_E;                           // 19170432
    unsigned short* wpk  = Hb + XB_E;                           // 10*59*144*32 = 2718720
    unsigned short* wpkF = wpk + (size_t)10 * NCH * CPG * 32;   // 59*64*32 = 120832
    float* blp  = (float*)(wpkF + (size_t)NCH * 64 * 32);       // 64
    float* w0p  = blp + 64;                                     // 1728
    float* logits = w0p + 1728;                                 // 131072*64 fp32

    // zero both activation buffers (halos must be 0; ws is poisoned)
    k_zero<<<2048, 256, 0, stream>>>((float*)ws, (2 * XB_E * 2) / 16);

    k_pack_hidden<<<2048, 256, 0, stream>>>(wres, wpk);
    k_pack_final<<<(NCH * 64 * 32 + 255) / 256, 256, 0, stream>>>(wl, wpkF);
    k_pack_small<<<7, 256, 0, stream>>>(w0, bl, w0p, blp);

    k_layer0<<<dim3(8, 256), dim3(64, 6), 0, stream>>>(data, w0p, b0, Xb);

    const size_t LSTRIDE = (size_t)NCH * CPG * 32;   // 271872
    for (int i = 0; i < 5; i++) {
        k_conv<false><<<dim3(4, 128), 512, 0, stream>>>(
            Xb, wpk + (size_t)(2 * i) * LSTRIDE, bres + (2 * i) * CPG, Xb, Hb);
        k_conv<true><<<dim3(4, 128), 512, 0, stream>>>(
            Hb, wpk + (size_t)(2 * i + 1) * LSTRIDE, bres + (2 * i + 1) * CPG, Xb, Xb);
    }

    k_logits<<<256, 256, 0, stream>>>(Xb, wpkF, blp, logits);
    k_softmax<<<dim3(2, 256), 256, 0, stream>>>(logits, out);
}

// Round 7
// 983.589 us; speedup vs baseline: 1.9700x; 1.9362x over previous
//
#include <hip/hip_runtime.h>

#define HH 256
#define WW 512
#define CPG 144
#define NKG 18                         // 144 ch = 18 groups of 8
#define WP 516                         // 512 + 2 left + 2 right
#define HPADR 258                      // 256 + 2 top halo rows
#define XB_E ((size_t)NKG * HPADR * WP * 8)   // 19170432 elems per activation buffer
#define NCH 59                         // K-chunks of 32 (K = 13*144 = 1872)
#define KREAL 1872
#define SCALE_F (2.0f / 47.0f)

typedef __attribute__((ext_vector_type(8))) short short8;
typedef __attribute__((ext_vector_type(4))) float floatx4;

__device__ __forceinline__ unsigned short f2bf(float f) {
    unsigned u = __builtin_bit_cast(unsigned, f);
    u += 0x7FFFu + ((u >> 16) & 1u);
    return (unsigned short)(u >> 16);
}
__device__ __forceinline__ float bf2f(unsigned short h) {
    unsigned u = ((unsigned)h) << 16;
    return __builtin_bit_cast(float, u);
}
__device__ __forceinline__ void async16(const void* g, void* l) {
    __builtin_amdgcn_global_load_lds(
        (const __attribute__((address_space(1))) unsigned int*)g,
        (__attribute__((address_space(3))) unsigned int*)l, 16, 0, 0);
}
// mask-B taps t=0..12: kh = t<5?0:(t<10?1:2), kw = t - {0,5,10}
__device__ __forceinline__ void tap_decode(int t, int& kh, int& kw) {
    kh = t < 5 ? 0 : (t < 10 ? 1 : 2);
    kw = t - (t < 5 ? 0 : (t < 10 ? 5 : 10));
}

// ---------------- zero workspace ------------------------------------------
__global__ void k_zero(float* __restrict__ p, size_t n4) {
    size_t i = (size_t)blockIdx.x * blockDim.x + threadIdx.x;
    size_t stride = (size_t)gridDim.x * blockDim.x;
    float4 z = make_float4(0.f, 0.f, 0.f, 0.f);
    for (; i < n4; i += stride) ((float4*)p)[i] = z;
}

// ---------------- weight packing (linear-K layout) ------------------------
// hidden: wpk[l][c][co144][kk32], K = c*32+kk -> (t = K/144, ci = K%144)
__global__ void k_pack_hidden(const float* __restrict__ wres, unsigned short* __restrict__ wpk) {
    const int total = 10 * NCH * CPG * 32;
    int i = blockIdx.x * blockDim.x + threadIdx.x;
    int stride = gridDim.x * blockDim.x;
    for (; i < total; i += stride) {
        int kk = i & 31;
        int q  = i >> 5;
        int co = q % CPG;
        int c  = (q / CPG) % NCH;
        int l  = q / (CPG * NCH);
        int K = c * 32 + kk;
        float v = 0.f;
        if (K < KREAL) {
            int t = K / CPG, ci = K - t * CPG;
            int kh, kw; tap_decode(t, kh, kw);
            v = wres[(((size_t)(l * CPG + co) * CPG + ci) * 5 + kh) * 5 + kw];
        }
        wpk[i] = f2bf(v);
    }
}
// final: wpkF[c][co64][kk32] (co>=49 zero)
__global__ void k_pack_final(const float* __restrict__ wl, unsigned short* __restrict__ wpkF) {
    const int total = NCH * 64 * 32;
    int i = blockIdx.x * blockDim.x + threadIdx.x;
    if (i >= total) return;
    int kk = i & 31;
    int co = (i >> 5) & 63;
    int c  = i >> 11;
    int K = c * 32 + kk;
    float v = 0.f;
    if (K < KREAL && co < 49) {
        int t = K / CPG, ci = K - t * CPG;
        int kh, kw; tap_decode(t, kh, kw);
        v = wl[(((size_t)co * CPG + ci) * 5 + kh) * 5 + kw];
    }
    wpkF[i] = f2bf(v);
}
// small: w0p[t*144+co] fp32 (12 mask-A taps) + blp[64] (bias pad)
__global__ void k_pack_small(const float* __restrict__ w0, const float* __restrict__ bl,
                             float* __restrict__ w0p, float* __restrict__ blp) {
    int i = blockIdx.x * blockDim.x + threadIdx.x;
    if (i < 12 * CPG) {
        int co = i % CPG, t = i / CPG;
        int kh, kw; tap_decode(t, kh, kw);   // t<12: mask-A (row2 only kw 0,1)
        w0p[i] = w0[co * 25 + kh * 5 + kw];
    } else if (i < 12 * CPG + 64) {
        int k = i - 12 * CPG;
        blp[k] = k < 49 ? bl[k] : 0.f;
    }
}

// ---------------- layer 0: data -> Xb bf16 blocked [kg][y][x][8] ----------
__global__ __launch_bounds__(384) void k_layer0(
    const float* __restrict__ data, const float* __restrict__ w0p,
    const float* __restrict__ b0, unsigned short* __restrict__ Xb) {
    const int lane = threadIdx.x;                 // 0..63
    const int x = blockIdx.x * 64 + lane;
    const int y = blockIdx.y;

    float xv[12];
#pragma unroll
    for (int t = 0; t < 12; t++) {
        int kh, kw; tap_decode(t, kh, kw);
        int yy = y + kh - 2, xx = x + kw - 2;
        xv[t] = (yy >= 0 && xx >= 0 && xx < WW) ? data[yy * WW + xx] * SCALE_F - 1.0f : 0.f;
    }
#pragma unroll
    for (int kgi = 0; kgi < 3; kgi++) {
        int kg = threadIdx.y * 3 + kgi;           // 0..17
        float a8[8];
#pragma unroll
        for (int j = 0; j < 8; j++) a8[j] = 0.f;
#pragma unroll
        for (int t = 0; t < 12; t++)
#pragma unroll
            for (int j = 0; j < 8; j++)
                a8[j] = fmaf(w0p[t * CPG + kg * 8 + j], xv[t], a8[j]);
        short8 o;
#pragma unroll
        for (int j = 0; j < 8; j++)
            o[j] = (short)f2bf(fmaxf(a8[j] + b0[kg * 8 + j], 0.f));
        *(short8*)&Xb[((size_t)(kg * HPADR + y + 2) * WP + (x + 2)) * 8] = o;
    }
}

// ---------------- hidden conv: stage-once LDS + register pipeline ---------
// block = 128px x 2 out rows x 144 co; 12 waves = (co-group 0..2) x (row 0..1)
// x (px-half 0..1). Wave tile Mf=4 (64px) x Nf=3 (48co) = 12 MFMA per
// (4 ds_read_b128 + 3 global b128). LDS: 4-row x 132px x 144ch window
// (152 KB) staged once; K-loop barrier-free with explicit 1-chunk register
// double buffer (a/b even-odd). Per-CU per chunk: MFMA 698 cyc vs B-L1 576
// vs LDS 565 -> MFMA-dominant by design.
template<bool RES>
__global__ __launch_bounds__(768, 3) void k_conv(
    const unsigned short* __restrict__ in,
    const unsigned short* __restrict__ wq,
    const float* __restrict__ bias,
    const unsigned short* __restrict__ res,
    unsigned short* __restrict__ out) {
    __shared__ __align__(16) unsigned short As[NKG][4][132][8];   // 152064 B
    const int tid  = threadIdx.x;
    const int lane = tid & 63;
    const int wid  = tid >> 6;          // 0..11
    const int ng   = wid % 3;           // co-group of 48
    const int r    = (wid / 3) & 1;     // output row 0..1
    const int ph   = wid / 6;           // px half (64 px)
    const int lr = lane & 15;
    const int lg = lane >> 4;

    // XCD-chunked swizzle: 512 blocks -> 64 consecutive per XCD
    const int fid = blockIdx.x + (int)gridDim.x * blockIdx.y;   // 0..511
    const int swz = (fid & 7) * 64 + (fid >> 3);
    const int x0 = (swz & 3) * 128;     // padded-col base of staged window
    const int y0 = (swz >> 2) * 2;      // padded-row base of staged window

    floatx4 acc[4][3];
#pragma unroll
    for (int m = 0; m < 4; m++)
#pragma unroll
        for (int n = 0; n < 3; n++) acc[m][n] = (floatx4)0.f;

    // ---- staging helpers ----
    auto stage_rows = [&](int r0) {     // rows r0, r0+1, px 0..127 via gll
        for (int i = wid; i < 72; i += 12) {
            int kg = i >> 2;
            int rr = r0 + ((i >> 1) & 1);
            int half = i & 1;
            async16(in + ((size_t)(kg * HPADR + y0 + rr) * WP + x0 + half * 64 + lane) * 8,
                    &As[kg][rr][half * 64][0]);
        }
    };

    // ---- K-loop helpers ----
    auto LDA = [&](int c, short8 (&a)[4]) {
        int g = c * 4 + lg;              // per-lane 8-ch group
        if (g > 233) g = 233;            // pad K: weights are 0 there
        int t = (g * 57) >> 10;          // g/18, exact for g<=233
        int kgp = g - t * 18;
        int kh, kw; tap_decode(t, kh, kw);
        const unsigned short* ap = &As[kgp][r + kh][ph * 64 + kw + lr][0];
#pragma unroll
        for (int m = 0; m < 4; ++m) a[m] = *(const short8*)(ap + m * 16 * 8);
    };
    auto LDB = [&](int c, short8 (&b)[3]) {
        const unsigned short* bp = wq + (size_t)c * 4608 + (ng * 48 + lr) * 32 + lg * 8;
#pragma unroll
        for (int n = 0; n < 3; ++n) b[n] = *(const short8*)(bp + n * 512);
    };
    auto CMP = [&](const short8 (&a)[4], const short8 (&b)[3]) {
#pragma unroll
        for (int m = 0; m < 4; ++m)
#pragma unroll
            for (int n = 0; n < 3; ++n)
                acc[m][n] = __builtin_amdgcn_mfma_f32_16x16x32_bf16(a[m], b[n], acc[m][n], 0, 0, 0);
    };

    // ---- prologue: stage rows 0-1; halo (all 4 rows) via direct copy ----
    stage_rows(0);
    if (tid < 288) {                    // halo px 128..131, all 4 rows
        int kg = tid >> 4;
        int rr = (tid >> 2) & 3;
        int pxl = 128 + (tid & 3);
        *(short8*)&As[kg][rr][pxl][0] =
            *(const short8*)(in + ((size_t)(kg * HPADR + y0 + rr) * WP + x0 + pxl) * 8);
    }
    asm volatile("s_waitcnt vmcnt(0) lgkmcnt(0)" ::: "memory");
    __builtin_amdgcn_s_barrier();
    __builtin_amdgcn_sched_barrier(0);
    stage_rows(2);                      // rows 2,3 in flight under kh=0 chunks

    // ---- phase 1: chunks 0..21 (all kh=0, rows 0-1 only) ----
    short8 a0[4], b0_[3], a1[4], b1_[3];
    LDA(0, a0); LDB(0, b0_);
#pragma unroll 1
    for (int c = 0; c < 20; c += 2) {
        LDA(c + 1, a1); LDB(c + 1, b1_);
        CMP(a0, b0_);
        LDA(c + 2, a0); LDB(c + 2, b0_);
        CMP(a1, b1_);
    }
    LDA(21, a1); LDB(21, b1_);
    CMP(a0, b0_);                       // chunk 20
    CMP(a1, b1_);                       // chunk 21
    asm volatile("s_waitcnt vmcnt(0)" ::: "memory");
    __builtin_amdgcn_s_barrier();
    __builtin_amdgcn_sched_barrier(0);

    // ---- phase 2: chunks 22..58 ----
    LDA(22, a0); LDB(22, b0_);
#pragma unroll 1
    for (int c = 22; c + 2 <= 58; c += 2) {
        LDA(c + 1, a1); LDB(c + 1, b1_);
        CMP(a0, b0_);
        LDA(c + 2, a0); LDB(c + 2, b0_);
        CMP(a1, b1_);
    }
    CMP(a0, b0_);                       // chunk 58

    // ---- epilogue ----
#pragma unroll
    for (int n = 0; n < 3; ++n) {
        int co = ng * 48 + n * 16 + lr;
        float bv = bias[co];
        const size_t pb = ((size_t)((co >> 3) * HPADR + y0 + 2 + r) * WP + (x0 + 2)) * 8 + (co & 7);
#pragma unroll
        for (int m = 0; m < 4; ++m)
#pragma unroll
            for (int rr = 0; rr < 4; ++rr) {
                int px = ph * 64 + m * 16 + lg * 4 + rr;
                size_t o = pb + (size_t)px * 8;
                float v = fmaxf(acc[m][n][rr] + bv, 0.f);
                if (RES) v += bf2f(res[o]);
                out[o] = f2bf(v);
            }
    }
}

// ---------------- final conv (144 -> 49 pad 64) -> fp32 logits ------------
// 4 independent waves per block, each: 128px x 64co (Mf=8, Nf=4).
__global__ __launch_bounds__(256, 2) void k_logits(
    const unsigned short* __restrict__ in,
    const unsigned short* __restrict__ wq,
    const float* __restrict__ blp,
    float* __restrict__ logits) {
    const int lane = threadIdx.x & 63;
    const int wid  = threadIdx.x >> 6;   // 0..3
    const int lr = lane & 15;
    const int lg = lane >> 4;
    const int tt = blockIdx.x * 4 + wid; // px-tile id 0..1023
    const int y  = tt >> 2;
    const int x0 = (tt & 3) * 128;

    floatx4 acc[8][4];
#pragma unroll
    for (int m = 0; m < 8; m++)
#pragma unroll
        for (int n = 0; n < 4; n++) acc[m][n] = (floatx4)0.f;

#pragma unroll 1
    for (int c = 0; c < NCH; ++c) {
        int g = c * 4 + lg;
        if (g > 233) g = 233;
        int t = (g * 57) >> 10;
        int kgp = g - t * 18;
        int kh, kw; tap_decode(t, kh, kw);
        const unsigned short* ap =
            in + ((size_t)(kgp * HPADR + y + kh) * WP + (x0 + kw + lr)) * 8;
        const unsigned short* bp =
            wq + ((size_t)c * 64 + lr) * 32 + lg * 8;
        short8 a[8], b[4];
#pragma unroll
        for (int m = 0; m < 8; ++m) a[m] = *(const short8*)(ap + m * 128);
#pragma unroll
        for (int n = 0; n < 4; ++n) b[n] = *(const short8*)(bp + n * 512);
#pragma unroll
        for (int m = 0; m < 8; ++m)
#pragma unroll
            for (int n = 0; n < 4; ++n)
                acc[m][n] = __builtin_amdgcn_mfma_f32_16x16x32_bf16(
                    a[m], b[n], acc[m][n], 0, 0, 0);
    }

#pragma unroll
    for (int n = 0; n < 4; ++n) {
        int co = n * 16 + lr;
        float bv = blp[co];
#pragma unroll
        for (int m = 0; m < 8; ++m)
#pragma unroll
            for (int rr = 0; rr < 4; ++rr) {
                int px = m * 16 + lg * 4 + rr;
                logits[((size_t)y * WW + x0 + px) * 64 + co] = acc[m][n][rr] + bv;
            }
    }
}

// ---------------- softmax + cdf -> d_out ----------------------------------
__global__ __launch_bounds__(256) void k_softmax(
    const float* __restrict__ lg, float* __restrict__ out) {
    const int px = blockIdx.x * 256 + threadIdx.x;
    const int y = blockIdx.y;
    const size_t p = (size_t)y * WW + px;
    const float* l = lg + p * 64;
    float v[49];
    float m = -1e30f;
#pragma unroll
    for (int k = 0; k < 49; k++) { v[k] = l[k]; m = fmaxf(m, v[k]); }
    float s = 0.f;
#pragma unroll
    for (int k = 0; k < 49; k++) {
        v[k] = exp2f((v[k] - m) * 1.44269504088896f);
        s += v[k];
    }
    const float inv = 65536.0f / s;
    out[p] = 0.f;
    float run = 0.f;
#pragma unroll
    for (int k = 0; k < 49; k++) {
        run += v[k];
        out[(size_t)(k + 1) * (HH * WW) + p] = run * inv;
    }
}

// ---------------- launcher -------------------------------------------------
extern "C" void kernel_launch(void* const* d_in, const int* in_sizes, int n_in,
                              void* d_out, int out_size, void* d_ws, size_t ws_size,
                              hipStream_t stream) {
    (void)in_sizes; (void)n_in; (void)out_size; (void)ws_size;
    const float* data = (const float*)d_in[0];
    const float* w0   = (const float*)d_in[1];
    const float* b0   = (const float*)d_in[2];
    const float* wres = (const float*)d_in[3];
    const float* bres = (const float*)d_in[4];
    const float* wl   = (const float*)d_in[5];
    const float* bl   = (const float*)d_in[6];
    float* out = (float*)d_out;

    char* ws = (char*)d_ws;
    unsigned short* Xb   = (unsigned short*)ws;                 // 19170432 elems
    unsigned short* Hb   = Xb + XB_E;                           // 19170432
    unsigned short* wpk  = Hb + XB_E;                           // 10*59*144*32 = 2718720
    unsigned short* wpkF = wpk + (size_t)10 * NCH * CPG * 32;   // 59*64*32 = 120832
    float* blp  = (float*)(wpkF + (size_t)NCH * 64 * 32);       // 64
    float* w0p  = blp + 64;                                     // 1728
    float* logits = w0p + 1728;                                 // 131072*64 fp32

    // zero both activation buffers (halos must be 0; ws is poisoned)
    k_zero<<<2048, 256, 0, stream>>>((float*)ws, (2 * XB_E * 2) / 16);

    k_pack_hidden<<<2048, 256, 0, stream>>>(wres, wpk);
    k_pack_final<<<(NCH * 64 * 32 + 255) / 256, 256, 0, stream>>>(wl, wpkF);
    k_pack_small<<<7, 256, 0, stream>>>(w0, bl, w0p, blp);

    k_layer0<<<dim3(8, 256), dim3(64, 6), 0, stream>>>(data, w0p, b0, Xb);

    const size_t LSTRIDE = (size_t)NCH * CPG * 32;   // 271872
    for (int i = 0; i < 5; i++) {
        k_conv<false><<<dim3(4, 128), 768, 0, stream>>>(
            Xb, wpk + (size_t)(2 * i) * LSTRIDE, bres + (2 * i) * CPG, Xb, Hb);
        k_conv<true><<<dim3(4, 128), 768, 0, stream>>>(
            Hb, wpk + (size_t)(2 * i + 1) * LSTRIDE, bres + (2 * i + 1) * CPG, Xb, Xb);
    }

    k_logits<<<256, 256, 0, stream>>>(Xb, wpkF, blp, logits);
    k_softmax<<<dim3(2, 256), 256, 0, stream>>>(logits, out);
}

// Round 8
// 977.133 us; speedup vs baseline: 1.9830x; 1.0066x over previous
//
#include <hip/hip_runtime.h>

#define HH 256
#define WW 512
#define CPG 144
#define NKG 18                         // 144 ch = 18 groups of 8
#define WP 516                         // 512 + 2 left + 2 right
#define HPADR 258                      // 256 + 2 top halo rows
#define XB_E ((size_t)NKG * HPADR * WP * 8)   // 19170432 elems per activation buffer
#define NCH 59                         // K-chunks of 32 (K = 13*144 = 1872)
#define KREAL 1872
#define SCALE_F (2.0f / 47.0f)

typedef __attribute__((ext_vector_type(8))) short short8;
typedef __attribute__((ext_vector_type(4))) float floatx4;

__device__ __forceinline__ unsigned short f2bf(float f) {
    unsigned u = __builtin_bit_cast(unsigned, f);
    u += 0x7FFFu + ((u >> 16) & 1u);
    return (unsigned short)(u >> 16);
}
__device__ __forceinline__ float bf2f(unsigned short h) {
    unsigned u = ((unsigned)h) << 16;
    return __builtin_bit_cast(float, u);
}
__device__ __forceinline__ void async16(const void* g, void* l) {
    __builtin_amdgcn_global_load_lds(
        (const __attribute__((address_space(1))) unsigned int*)g,
        (__attribute__((address_space(3))) unsigned int*)l, 16, 0, 0);
}
// mask-B taps t=0..12: kh = t<5?0:(t<10?1:2), kw = t - {0,5,10}
__device__ __forceinline__ void tap_decode(int t, int& kh, int& kw) {
    kh = t < 5 ? 0 : (t < 10 ? 1 : 2);
    kw = t - (t < 5 ? 0 : (t < 10 ? 5 : 10));
}

// ---------------- zero workspace ------------------------------------------
__global__ void k_zero(float* __restrict__ p, size_t n4) {
    size_t i = (size_t)blockIdx.x * blockDim.x + threadIdx.x;
    size_t stride = (size_t)gridDim.x * blockDim.x;
    float4 z = make_float4(0.f, 0.f, 0.f, 0.f);
    for (; i < n4; i += stride) ((float4*)p)[i] = z;
}

// ---------------- weight packing (linear-K layout) ------------------------
// hidden: wpk[l][c][co144][kk32], K = c*32+kk -> (t = K/144, ci = K%144)
__global__ void k_pack_hidden(const float* __restrict__ wres, unsigned short* __restrict__ wpk) {
    const int total = 10 * NCH * CPG * 32;
    int i = blockIdx.x * blockDim.x + threadIdx.x;
    int stride = gridDim.x * blockDim.x;
    for (; i < total; i += stride) {
        int kk = i & 31;
        int q  = i >> 5;
        int co = q % CPG;
        int c  = (q / CPG) % NCH;
        int l  = q / (CPG * NCH);
        int K = c * 32 + kk;
        float v = 0.f;
        if (K < KREAL) {
            int t = K / CPG, ci = K - t * CPG;
            int kh, kw; tap_decode(t, kh, kw);
            v = wres[(((size_t)(l * CPG + co) * CPG + ci) * 5 + kh) * 5 + kw];
        }
        wpk[i] = f2bf(v);
    }
}
// final: wpkF[c][co64][kk32] (co>=49 zero)
__global__ void k_pack_final(const float* __restrict__ wl, unsigned short* __restrict__ wpkF) {
    const int total = NCH * 64 * 32;
    int i = blockIdx.x * blockDim.x + threadIdx.x;
    if (i >= total) return;
    int kk = i & 31;
    int co = (i >> 5) & 63;
    int c  = i >> 11;
    int K = c * 32 + kk;
    float v = 0.f;
    if (K < KREAL && co < 49) {
        int t = K / CPG, ci = K - t * CPG;
        int kh, kw; tap_decode(t, kh, kw);
        v = wl[(((size_t)co * CPG + ci) * 5 + kh) * 5 + kw];
    }
    wpkF[i] = f2bf(v);
}
// small: w0p[t*144+co] fp32 (12 mask-A taps) + blp[64] (bias pad)
__global__ void k_pack_small(const float* __restrict__ w0, const float* __restrict__ bl,
                             float* __restrict__ w0p, float* __restrict__ blp) {
    int i = blockIdx.x * blockDim.x + threadIdx.x;
    if (i < 12 * CPG) {
        int co = i % CPG, t = i / CPG;
        int kh, kw; tap_decode(t, kh, kw);   // t<12: mask-A (row2 only kw 0,1)
        w0p[i] = w0[co * 25 + kh * 5 + kw];
    } else if (i < 12 * CPG + 64) {
        int k = i - 12 * CPG;
        blp[k] = k < 49 ? bl[k] : 0.f;
    }
}

// ---------------- layer 0: data -> Xb bf16 blocked [kg][y][x][8] ----------
__global__ __launch_bounds__(384) void k_layer0(
    const float* __restrict__ data, const float* __restrict__ w0p,
    const float* __restrict__ b0, unsigned short* __restrict__ Xb) {
    const int lane = threadIdx.x;                 // 0..63
    const int x = blockIdx.x * 64 + lane;
    const int y = blockIdx.y;

    float xv[12];
#pragma unroll
    for (int t = 0; t < 12; t++) {
        int kh, kw; tap_decode(t, kh, kw);
        int yy = y + kh - 2, xx = x + kw - 2;
        xv[t] = (yy >= 0 && xx >= 0 && xx < WW) ? data[yy * WW + xx] * SCALE_F - 1.0f : 0.f;
    }
#pragma unroll
    for (int kgi = 0; kgi < 3; kgi++) {
        int kg = threadIdx.y * 3 + kgi;           // 0..17
        float a8[8];
#pragma unroll
        for (int j = 0; j < 8; j++) a8[j] = 0.f;
#pragma unroll
        for (int t = 0; t < 12; t++)
#pragma unroll
            for (int j = 0; j < 8; j++)
                a8[j] = fmaf(w0p[t * CPG + kg * 8 + j], xv[t], a8[j]);
        short8 o;
#pragma unroll
        for (int j = 0; j < 8; j++)
            o[j] = (short)f2bf(fmaxf(a8[j] + b0[kg * 8 + j], 0.f));
        *(short8*)&Xb[((size_t)(kg * HPADR + y + 2) * WP + (x + 2)) * 8] = o;
    }
}

// ---------------- hidden conv: stage-once LDS + register pipeline ---------
// block = 128px x 2 out rows x 144 co; 12 waves = (co-group 0..2) x (row 0..1)
// x (px-half 0..1). Wave tile Mf=4 (64px) x Nf=3 (48co) = 12 MFMA per
// (4 ds_read_b128 + 1 ds_read_b32 + 3 global b128). ALL staging (4 rows,
// 152 KB) + LDS offset table happens in the prologue with ONE drain+barrier;
// the 59-chunk K-loop is then barrier-free with precise counted vmcnt waits
// (no outstanding gll to poison the counts) and table-driven A addressing.
template<bool RES>
__global__ __launch_bounds__(768, 3) void k_conv(
    const unsigned short* __restrict__ in,
    const unsigned short* __restrict__ wq,
    const float* __restrict__ bias,
    const unsigned short* __restrict__ res,
    unsigned short* __restrict__ out) {
    __shared__ __align__(16) unsigned short As[NKG][4][132][8];   // 152064 B
    __shared__ unsigned toff[NCH][4];                             // 944 B
    const int tid  = threadIdx.x;
    const int lane = tid & 63;
    const int wid  = tid >> 6;          // 0..11
    const int ng   = wid % 3;           // co-group of 48
    const int r    = (wid / 3) & 1;     // output row 0..1
    const int ph   = wid / 6;           // px half (64 px)
    const int lr = lane & 15;
    const int lg = lane >> 4;

    // XCD-chunked swizzle: 512 blocks -> 64 consecutive per XCD
    const int fid = blockIdx.x + (int)gridDim.x * blockIdx.y;   // 0..511
    const int swz = (fid & 7) * 64 + (fid >> 3);
    const int x0 = (swz & 3) * 128;     // padded-col base of staged window
    const int y0 = (swz >> 2) * 2;      // padded-row base of staged window

    floatx4 acc[4][3];
#pragma unroll
    for (int m = 0; m < 4; m++)
#pragma unroll
        for (int n = 0; n < 3; n++) acc[m][n] = (floatx4)0.f;

    // ---- prologue: stage ALL 4 rows + halo + offset table, one drain ----
    for (int i = wid; i < 144; i += 12) {       // kg(18) x row(4) x half(2)
        int half = i & 1;
        int rr   = (i >> 1) & 3;
        int kg   = i >> 3;
        async16(in + ((size_t)(kg * HPADR + y0 + rr) * WP + x0 + half * 64 + lane) * 8,
                &As[kg][rr][half * 64][0]);
    }
    if (tid < 288) {                    // halo px 128..131, all 4 rows
        int kg = tid >> 4;
        int rr = (tid >> 2) & 3;
        int pxl = 128 + (tid & 3);
        *(short8*)&As[kg][rr][pxl][0] =
            *(const short8*)(in + ((size_t)(kg * HPADR + y0 + rr) * WP + x0 + pxl) * 8);
    }
    if (tid < NCH * 4) {                // LDS byte-offset table (chunk, lg)
        int c = tid >> 2, l2 = tid & 3;
        int g = c * 4 + l2;             // 8-ch group index
        if (g > 233) g = 233;           // pad K: weights are 0 there
        int t = (g * 57) >> 10;         // g/18, exact for g<=233
        int kgp = g - t * 18;
        int kh, kw; tap_decode(t, kh, kw);
        toff[c][l2] = (unsigned)(((kgp * 4 + kh) * 132 + kw) * 16);
    }
    asm volatile("s_waitcnt vmcnt(0) lgkmcnt(0)" ::: "memory");
    __builtin_amdgcn_s_barrier();
    __builtin_amdgcn_sched_barrier(0);

    // ---- K-loop helpers ----
    const char* abase = (const char*)&As[0][r][ph * 64 + lr][0];
    auto LDA = [&](int c, short8 (&a)[4]) {
        const unsigned short* ap = (const unsigned short*)(abase + toff[c][lg]);
#pragma unroll
        for (int m = 0; m < 4; ++m) a[m] = *(const short8*)(ap + m * 16 * 8);
    };
    auto LDB = [&](int c, short8 (&b)[3]) {
        const unsigned short* bp = wq + (size_t)c * 4608 + (ng * 48 + lr) * 32 + lg * 8;
#pragma unroll
        for (int n = 0; n < 3; ++n) b[n] = *(const short8*)(bp + n * 512);
    };
    auto CMP = [&](const short8 (&a)[4], const short8 (&b)[3]) {
#pragma unroll
        for (int m = 0; m < 4; ++m)
#pragma unroll
            for (int n = 0; n < 3; ++n)
                acc[m][n] = __builtin_amdgcn_mfma_f32_16x16x32_bf16(a[m], b[n], acc[m][n], 0, 0, 0);
    };

    // ---- K-loop: 59 chunks, 1-chunk register double buffer, no barriers ----
    short8 a0[4], b0_[3], a1[4], b1_[3];
    LDB(0, b0_); LDA(0, a0);
#pragma unroll 1
    for (int c = 0; c < 58; c += 2) {
        LDB(c + 1, b1_); LDA(c + 1, a1);
        CMP(a0, b0_);
        LDB(c + 2, b0_); LDA(c + 2, a0);
        CMP(a1, b1_);
    }
    CMP(a0, b0_);                       // chunk 58

    // ---- epilogue ----
#pragma unroll
    for (int n = 0; n < 3; ++n) {
        int co = ng * 48 + n * 16 + lr;
        float bv = bias[co];
        const size_t pb = ((size_t)((co >> 3) * HPADR + y0 + 2 + r) * WP + (x0 + 2)) * 8 + (co & 7);
#pragma unroll
        for (int m = 0; m < 4; ++m)
#pragma unroll
            for (int rr = 0; rr < 4; ++rr) {
                int px = ph * 64 + m * 16 + lg * 4 + rr;
                size_t o = pb + (size_t)px * 8;
                float v = fmaxf(acc[m][n][rr] + bv, 0.f);
                if (RES) v += bf2f(res[o]);
                out[o] = f2bf(v);
            }
    }
}

// ---------------- final conv (144 -> 49 pad 64) -> fp32 logits ------------
// 4 independent waves per block, each: 128px x 64co (Mf=8, Nf=4).
__global__ __launch_bounds__(256, 2) void k_logits(
    const unsigned short* __restrict__ in,
    const unsigned short* __restrict__ wq,
    const float* __restrict__ blp,
    float* __restrict__ logits) {
    const int lane = threadIdx.x & 63;
    const int wid  = threadIdx.x >> 6;   // 0..3
    const int lr = lane & 15;
    const int lg = lane >> 4;
    const int tt = blockIdx.x * 4 + wid; // px-tile id 0..1023
    const int y  = tt >> 2;
    const int x0 = (tt & 3) * 128;

    floatx4 acc[8][4];
#pragma unroll
    for (int m = 0; m < 8; m++)
#pragma unroll
        for (int n = 0; n < 4; n++) acc[m][n] = (floatx4)0.f;

#pragma unroll 1
    for (int c = 0; c < NCH; ++c) {
        int g = c * 4 + lg;
        if (g > 233) g = 233;
        int t = (g * 57) >> 10;
        int kgp = g - t * 18;
        int kh, kw; tap_decode(t, kh, kw);
        const unsigned short* ap =
            in + ((size_t)(kgp * HPADR + y + kh) * WP + (x0 + kw + lr)) * 8;
        const unsigned short* bp =
            wq + ((size_t)c * 64 + lr) * 32 + lg * 8;
        short8 a[8], b[4];
#pragma unroll
        for (int m = 0; m < 8; ++m) a[m] = *(const short8*)(ap + m * 128);
#pragma unroll
        for (int n = 0; n < 4; ++n) b[n] = *(const short8*)(bp + n * 512);
#pragma unroll
        for (int m = 0; m < 8; ++m)
#pragma unroll
            for (int n = 0; n < 4; ++n)
                acc[m][n] = __builtin_amdgcn_mfma_f32_16x16x32_bf16(
                    a[m], b[n], acc[m][n], 0, 0, 0);
    }

#pragma unroll
    for (int n = 0; n < 4; ++n) {
        int co = n * 16 + lr;
        float bv = blp[co];
#pragma unroll
        for (int m = 0; m < 8; ++m)
#pragma unroll
            for (int rr = 0; rr < 4; ++rr) {
                int px = m * 16 + lg * 4 + rr;
                logits[((size_t)y * WW + x0 + px) * 64 + co] = acc[m][n][rr] + bv;
            }
    }
}

// ---------------- softmax + cdf -> d_out ----------------------------------
__global__ __launch_bounds__(256) void k_softmax(
    const float* __restrict__ lg, float* __restrict__ out) {
    const int px = blockIdx.x * 256 + threadIdx.x;
    const int y = blockIdx.y;
    const size_t p = (size_t)y * WW + px;
    const float* l = lg + p * 64;
    float v[49];
    float m = -1e30f;
#pragma unroll
    for (int k = 0; k < 49; k++) { v[k] = l[k]; m = fmaxf(m, v[k]); }
    float s = 0.f;
#pragma unroll
    for (int k = 0; k < 49; k++) {
        v[k] = exp2f((v[k] - m) * 1.44269504088896f);
        s += v[k];
    }
    const float inv = 65536.0f / s;
    out[p] = 0.f;
    float run = 0.f;
#pragma unroll
    for (int k = 0; k < 49; k++) {
        run += v[k];
        out[(size_t)(k + 1) * (HH * WW) + p] = run * inv;
    }
}

// ---------------- launcher -------------------------------------------------
extern "C" void kernel_launch(void* const* d_in, const int* in_sizes, int n_in,
                              void* d_out, int out_size, void* d_ws, size_t ws_size,
                              hipStream_t stream) {
    (void)in_sizes; (void)n_in; (void)out_size; (void)ws_size;
    const float* data = (const float*)d_in[0];
    const float* w0   = (const float*)d_in[1];
    const float* b0   = (const float*)d_in[2];
    const float* wres = (const float*)d_in[3];
    const float* bres = (const float*)d_in[4];
    const float* wl   = (const float*)d_in[5];
    const float* bl   = (const float*)d_in[6];
    float* out = (float*)d_out;

    char* ws = (char*)d_ws;
    unsigned short* Xb   = (unsigned short*)ws;                 // 19170432 elems
    unsigned short* Hb   = Xb + XB_E;                           // 19170432
    unsigned short* wpk  = Hb + XB_E;                           // 10*59*144*32 = 2718720
    unsigned short* wpkF = wpk + (size_t)10 * NCH * CPG * 32;   // 59*64*32 = 120832
    float* blp  = (float*)(wpkF + (size_t)NCH * 64 * 32);       // 64
    float* w0p  = blp + 64;                                     // 1728
    float* logits = w0p + 1728;                                 // 131072*64 fp32

    // zero both activation buffers (halos must be 0; ws is poisoned)
    k_zero<<<2048, 256, 0, stream>>>((float*)ws, (2 * XB_E * 2) / 16);

    k_pack_hidden<<<2048, 256, 0, stream>>>(wres, wpk);
    k_pack_final<<<(NCH * 64 * 32 + 255) / 256, 256, 0, stream>>>(wl, wpkF);
    k_pack_small<<<7, 256, 0, stream>>>(w0, bl, w0p, blp);

    k_layer0<<<dim3(8, 256), dim3(64, 6), 0, stream>>>(data, w0p, b0, Xb);

    const size_t LSTRIDE = (size_t)NCH * CPG * 32;   // 271872
    for (int i = 0; i < 5; i++) {
        k_conv<false><<<dim3(4, 128), 768, 0, stream>>>(
            Xb, wpk + (size_t)(2 * i) * LSTRIDE, bres + (2 * i) * CPG, Xb, Hb);
        k_conv<true><<<dim3(4, 128), 768, 0, stream>>>(
            Hb, wpk + (size_t)(2 * i + 1) * LSTRIDE, bres + (2 * i + 1) * CPG, Xb, Xb);
    }

    k_logits<<<256, 256, 0, stream>>>(Xb, wpkF, blp, logits);
    k_softmax<<<dim3(2, 256), 256, 0, stream>>>(logits, out);
}

// Round 9
// 911.292 us; speedup vs baseline: 2.1263x; 1.0723x over previous
//
#include <hip/hip_runtime.h>

#define HH 256
#define WW 512
#define CPG 144
#define NKG 18                         // 144 ch = 18 groups of 8
#define WP 516                         // 512 + 2 left + 2 right
#define HPADR 258                      // 256 + 2 top halo rows
#define XB_E ((size_t)NKG * HPADR * WP * 8)   // 19170432 elems per activation buffer
#define NCH 59                         // K-chunks of 32 (K = 13*144 = 1872)
#define KREAL 1872
#define SCALE_F (2.0f / 47.0f)

typedef __attribute__((ext_vector_type(8))) short short8;
typedef __attribute__((ext_vector_type(4))) float floatx4;

__device__ __forceinline__ unsigned short f2bf(float f) {
    unsigned u = __builtin_bit_cast(unsigned, f);
    u += 0x7FFFu + ((u >> 16) & 1u);
    return (unsigned short)(u >> 16);
}
__device__ __forceinline__ float bf2f(unsigned short h) {
    unsigned u = ((unsigned)h) << 16;
    return __builtin_bit_cast(float, u);
}
__device__ __forceinline__ void async16(const void* g, void* l) {
    __builtin_amdgcn_global_load_lds(
        (const __attribute__((address_space(1))) unsigned int*)g,
        (__attribute__((address_space(3))) unsigned int*)l, 16, 0, 0);
}
// mask-B taps t=0..12: kh = t<5?0:(t<10?1:2), kw = t - {0,5,10}
__device__ __forceinline__ void tap_decode(int t, int& kh, int& kw) {
    kh = t < 5 ? 0 : (t < 10 ? 1 : 2);
    kw = t - (t < 5 ? 0 : (t < 10 ? 5 : 10));
}

// ---------------- zero workspace ------------------------------------------
__global__ void k_zero(float* __restrict__ p, size_t n4) {
    size_t i = (size_t)blockIdx.x * blockDim.x + threadIdx.x;
    size_t stride = (size_t)gridDim.x * blockDim.x;
    float4 z = make_float4(0.f, 0.f, 0.f, 0.f);
    for (; i < n4; i += stride) ((float4*)p)[i] = z;
}

// ---------------- weight packing (linear-K layout) ------------------------
// hidden: wpk[l][c][co144][kk32], K = c*32+kk -> (t = K/144, ci = K%144)
__global__ void k_pack_hidden(const float* __restrict__ wres, unsigned short* __restrict__ wpk) {
    const int total = 10 * NCH * CPG * 32;
    int i = blockIdx.x * blockDim.x + threadIdx.x;
    int stride = gridDim.x * blockDim.x;
    for (; i < total; i += stride) {
        int kk = i & 31;
        int q  = i >> 5;
        int co = q % CPG;
        int c  = (q / CPG) % NCH;
        int l  = q / (CPG * NCH);
        int K = c * 32 + kk;
        float v = 0.f;
        if (K < KREAL) {
            int t = K / CPG, ci = K - t * CPG;
            int kh, kw; tap_decode(t, kh, kw);
            v = wres[(((size_t)(l * CPG + co) * CPG + ci) * 5 + kh) * 5 + kw];
        }
        wpk[i] = f2bf(v);
    }
}
// final: wpkF[c][co64][kk32] (co>=49 zero)
__global__ void k_pack_final(const float* __restrict__ wl, unsigned short* __restrict__ wpkF) {
    const int total = NCH * 64 * 32;
    int i = blockIdx.x * blockDim.x + threadIdx.x;
    if (i >= total) return;
    int kk = i & 31;
    int co = (i >> 5) & 63;
    int c  = i >> 11;
    int K = c * 32 + kk;
    float v = 0.f;
    if (K < KREAL && co < 49) {
        int t = K / CPG, ci = K - t * CPG;
        int kh, kw; tap_decode(t, kh, kw);
        v = wl[(((size_t)co * CPG + ci) * 5 + kh) * 5 + kw];
    }
    wpkF[i] = f2bf(v);
}
// small: w0p[t*144+co] fp32 (12 mask-A taps) + blp[64] (bias pad)
__global__ void k_pack_small(const float* __restrict__ w0, const float* __restrict__ bl,
                             float* __restrict__ w0p, float* __restrict__ blp) {
    int i = blockIdx.x * blockDim.x + threadIdx.x;
    if (i < 12 * CPG) {
        int co = i % CPG, t = i / CPG;
        int kh, kw; tap_decode(t, kh, kw);   // t<12: mask-A (row2 only kw 0,1)
        w0p[i] = w0[co * 25 + kh * 5 + kw];
    } else if (i < 12 * CPG + 64) {
        int k = i - 12 * CPG;
        blp[k] = k < 49 ? bl[k] : 0.f;
    }
}

// ---------------- layer 0: data -> Xb bf16 blocked [kg][y][x][8] ----------
__global__ __launch_bounds__(384) void k_layer0(
    const float* __restrict__ data, const float* __restrict__ w0p,
    const float* __restrict__ b0, unsigned short* __restrict__ Xb) {
    const int lane = threadIdx.x;                 // 0..63
    const int x = blockIdx.x * 64 + lane;
    const int y = blockIdx.y;

    float xv[12];
#pragma unroll
    for (int t = 0; t < 12; t++) {
        int kh, kw; tap_decode(t, kh, kw);
        int yy = y + kh - 2, xx = x + kw - 2;
        xv[t] = (yy >= 0 && xx >= 0 && xx < WW) ? data[yy * WW + xx] * SCALE_F - 1.0f : 0.f;
    }
#pragma unroll
    for (int kgi = 0; kgi < 3; kgi++) {
        int kg = threadIdx.y * 3 + kgi;           // 0..17
        float a8[8];
#pragma unroll
        for (int j = 0; j < 8; j++) a8[j] = 0.f;
#pragma unroll
        for (int t = 0; t < 12; t++)
#pragma unroll
            for (int j = 0; j < 8; j++)
                a8[j] = fmaf(w0p[t * CPG + kg * 8 + j], xv[t], a8[j]);
        short8 o;
#pragma unroll
        for (int j = 0; j < 8; j++)
            o[j] = (short)f2bf(fmaxf(a8[j] + b0[kg * 8 + j], 0.f));
        *(short8*)&Xb[((size_t)(kg * HPADR + y + 2) * WP + (x + 2)) * 8] = o;
    }
}

// ---------------- hidden conv: stage-once LDS + PINNED register pipeline --
// block = 128px x 2 out rows x 144 co; 12 waves = (co-group 0..2) x (row 0..1)
// x (px-half 0..1). Wave tile Mf=4 x Nf=3 = 12 MFMA per (1 ds_b32 + 4
// ds_b128 + 3 global b128). sched_barrier(0) fences pin the {loads c+1} |
// {MFMA c} interleave so the double buffer survives regalloc; setprio(1)
// wraps the MFMA cluster.
template<bool RES>
__global__ __launch_bounds__(768, 3) void k_conv(
    const unsigned short* __restrict__ in,
    const unsigned short* __restrict__ wq,
    const float* __restrict__ bias,
    const unsigned short* __restrict__ res,
    unsigned short* __restrict__ out) {
    __shared__ __align__(16) unsigned short As[NKG][4][132][8];   // 152064 B
    __shared__ unsigned toff[NCH][4];                             // 944 B
    const int tid  = threadIdx.x;
    const int lane = tid & 63;
    const int wid  = tid >> 6;          // 0..11
    const int ng   = wid % 3;           // co-group of 48
    const int r    = (wid / 3) & 1;     // output row 0..1
    const int ph   = wid / 6;           // px half (64 px)
    const int lr = lane & 15;
    const int lg = lane >> 4;

    // XCD-chunked swizzle: 512 blocks -> 64 consecutive per XCD
    const int fid = blockIdx.x + (int)gridDim.x * blockIdx.y;   // 0..511
    const int swz = (fid & 7) * 64 + (fid >> 3);
    const int x0 = (swz & 3) * 128;     // padded-col base of staged window
    const int y0 = (swz >> 2) * 2;      // padded-row base of staged window

    floatx4 acc[4][3];
#pragma unroll
    for (int m = 0; m < 4; m++)
#pragma unroll
        for (int n = 0; n < 3; n++) acc[m][n] = (floatx4)0.f;

    // ---- prologue: stage ALL 4 rows + halo + offset table, one drain ----
    for (int i = wid; i < 144; i += 12) {       // kg(18) x row(4) x half(2)
        int half = i & 1;
        int rr   = (i >> 1) & 3;
        int kg   = i >> 3;
        async16(in + ((size_t)(kg * HPADR + y0 + rr) * WP + x0 + half * 64 + lane) * 8,
                &As[kg][rr][half * 64][0]);
    }
    if (tid < 288) {                    // halo px 128..131, all 4 rows
        int kg = tid >> 4;
        int rr = (tid >> 2) & 3;
        int pxl = 128 + (tid & 3);
        *(short8*)&As[kg][rr][pxl][0] =
            *(const short8*)(in + ((size_t)(kg * HPADR + y0 + rr) * WP + x0 + pxl) * 8);
    }
    if (tid < NCH * 4) {                // LDS byte-offset table (chunk, lg)
        int c = tid >> 2, l2 = tid & 3;
        int g = c * 4 + l2;             // 8-ch group index
        if (g > 233) g = 233;           // pad K: weights are 0 there
        int t = (g * 57) >> 10;         // g/18, exact for g<=233
        int kgp = g - t * 18;
        int kh, kw; tap_decode(t, kh, kw);
        toff[c][l2] = (unsigned)(((kgp * 4 + kh) * 132 + kw) * 16);
    }
    asm volatile("s_waitcnt vmcnt(0) lgkmcnt(0)" ::: "memory");
    __builtin_amdgcn_s_barrier();
    __builtin_amdgcn_sched_barrier(0);

    // ---- K-loop helpers ----
    const char* abase = (const char*)&As[0][r][ph * 64 + lr][0];
    auto LDA = [&](int c, short8 (&a)[4]) {
        const unsigned short* ap = (const unsigned short*)(abase + toff[c][lg]);
#pragma unroll
        for (int m = 0; m < 4; ++m) a[m] = *(const short8*)(ap + m * 16 * 8);
    };
    auto LDB = [&](int c, short8 (&b)[3]) {
        const unsigned short* bp = wq + (size_t)c * 4608 + (ng * 48 + lr) * 32 + lg * 8;
#pragma unroll
        for (int n = 0; n < 3; ++n) b[n] = *(const short8*)(bp + n * 512);
    };
    auto CMP = [&](const short8 (&a)[4], const short8 (&b)[3]) {
        __builtin_amdgcn_sched_barrier(0);
        __builtin_amdgcn_s_setprio(1);
#pragma unroll
        for (int m = 0; m < 4; ++m)
#pragma unroll
            for (int n = 0; n < 3; ++n)
                acc[m][n] = __builtin_amdgcn_mfma_f32_16x16x32_bf16(a[m], b[n], acc[m][n], 0, 0, 0);
        __builtin_amdgcn_s_setprio(0);
        __builtin_amdgcn_sched_barrier(0);
    };

    // ---- K-loop: 59 chunks, pinned 1-chunk register double buffer --------
    short8 a0[4], b0_[3], a1[4], b1_[3];
    LDB(0, b0_); LDA(0, a0);
#pragma unroll 1
    for (int c = 0; c < 58; c += 2) {
        LDB(c + 1, b1_); LDA(c + 1, a1);
        CMP(a0, b0_);                   // fenced + setprio inside
        LDB(c + 2, b0_); LDA(c + 2, a0);
        CMP(a1, b1_);
    }
    CMP(a0, b0_);                       // chunk 58

    // ---- epilogue ----
#pragma unroll
    for (int n = 0; n < 3; ++n) {
        int co = ng * 48 + n * 16 + lr;
        float bv = bias[co];
        const size_t pb = ((size_t)((co >> 3) * HPADR + y0 + 2 + r) * WP + (x0 + 2)) * 8 + (co & 7);
#pragma unroll
        for (int m = 0; m < 4; ++m)
#pragma unroll
            for (int rr = 0; rr < 4; ++rr) {
                int px = ph * 64 + m * 16 + lg * 4 + rr;
                size_t o = pb + (size_t)px * 8;
                float v = fmaxf(acc[m][n][rr] + bv, 0.f);
                if (RES) v += bf2f(res[o]);
                out[o] = f2bf(v);
            }
    }
}

// ---------------- final conv (144 -> 49 pad 64) -> fp32 logits ------------
// Same stage-once LDS structure: 8 waves = (co-grp 0..1) x (row 0..1) x
// (px-half 0..1); wave tile Mf=4 x Nf=2.
__global__ __launch_bounds__(512, 2) void k_logits(
    const unsigned short* __restrict__ in,
    const unsigned short* __restrict__ wq,
    const float* __restrict__ blp,
    float* __restrict__ logits) {
    __shared__ __align__(16) unsigned short As[NKG][4][132][8];   // 152064 B
    __shared__ unsigned toff[NCH][4];
    const int tid  = threadIdx.x;
    const int lane = tid & 63;
    const int wid  = tid >> 6;          // 0..7
    const int ng   = wid & 1;           // co-group of 32
    const int r    = (wid >> 1) & 1;    // output row 0..1
    const int ph   = wid >> 2;          // px half (64 px)
    const int lr = lane & 15;
    const int lg = lane >> 4;

    const int fid = blockIdx.x + (int)gridDim.x * blockIdx.y;   // 0..511
    const int swz = (fid & 7) * 64 + (fid >> 3);
    const int x0 = (swz & 3) * 128;
    const int y0 = (swz >> 2) * 2;

    floatx4 acc[4][2];
#pragma unroll
    for (int m = 0; m < 4; m++)
#pragma unroll
        for (int n = 0; n < 2; n++) acc[m][n] = (floatx4)0.f;

    // ---- prologue ----
    for (int i = wid; i < 144; i += 8) {
        int half = i & 1;
        int rr   = (i >> 1) & 3;
        int kg   = i >> 3;
        async16(in + ((size_t)(kg * HPADR + y0 + rr) * WP + x0 + half * 64 + lane) * 8,
                &As[kg][rr][half * 64][0]);
    }
    if (tid < 288) {
        int kg = tid >> 4;
        int rr = (tid >> 2) & 3;
        int pxl = 128 + (tid & 3);
        *(short8*)&As[kg][rr][pxl][0] =
            *(const short8*)(in + ((size_t)(kg * HPADR + y0 + rr) * WP + x0 + pxl) * 8);
    }
    if (tid < NCH * 4) {
        int c = tid >> 2, l2 = tid & 3;
        int g = c * 4 + l2;
        if (g > 233) g = 233;
        int t = (g * 57) >> 10;
        int kgp = g - t * 18;
        int kh, kw; tap_decode(t, kh, kw);
        toff[c][l2] = (unsigned)(((kgp * 4 + kh) * 132 + kw) * 16);
    }
    asm volatile("s_waitcnt vmcnt(0) lgkmcnt(0)" ::: "memory");
    __builtin_amdgcn_s_barrier();
    __builtin_amdgcn_sched_barrier(0);

    const char* abase = (const char*)&As[0][r][ph * 64 + lr][0];
    auto LDA = [&](int c, short8 (&a)[4]) {
        const unsigned short* ap = (const unsigned short*)(abase + toff[c][lg]);
#pragma unroll
        for (int m = 0; m < 4; ++m) a[m] = *(const short8*)(ap + m * 16 * 8);
    };
    auto LDB = [&](int c, short8 (&b)[2]) {
        const unsigned short* bp = wq + (size_t)c * 2048 + (ng * 32 + lr) * 32 + lg * 8;
#pragma unroll
        for (int n = 0; n < 2; ++n) b[n] = *(const short8*)(bp + n * 512);
    };
    auto CMP = [&](const short8 (&a)[4], const short8 (&b)[2]) {
        __builtin_amdgcn_sched_barrier(0);
        __builtin_amdgcn_s_setprio(1);
#pragma unroll
        for (int m = 0; m < 4; ++m)
#pragma unroll
            for (int n = 0; n < 2; ++n)
                acc[m][n] = __builtin_amdgcn_mfma_f32_16x16x32_bf16(a[m], b[n], acc[m][n], 0, 0, 0);
        __builtin_amdgcn_s_setprio(0);
        __builtin_amdgcn_sched_barrier(0);
    };

    short8 a0[4], b0_[2], a1[4], b1_[2];
    LDB(0, b0_); LDA(0, a0);
#pragma unroll 1
    for (int c = 0; c < 58; c += 2) {
        LDB(c + 1, b1_); LDA(c + 1, a1);
        CMP(a0, b0_);
        LDB(c + 2, b0_); LDA(c + 2, a0);
        CMP(a1, b1_);
    }
    CMP(a0, b0_);                       // chunk 58

#pragma unroll
    for (int n = 0; n < 2; ++n) {
        int co = ng * 32 + n * 16 + lr;
        float bv = blp[co];
#pragma unroll
        for (int m = 0; m < 4; ++m)
#pragma unroll
            for (int rr = 0; rr < 4; ++rr) {
                int px = ph * 64 + m * 16 + lg * 4 + rr;
                logits[((size_t)(y0 + r) * WW + x0 + px) * 64 + co] = acc[m][n][rr] + bv;
            }
    }
}

// ---------------- softmax + cdf -> d_out ----------------------------------
__global__ __launch_bounds__(256) void k_softmax(
    const float* __restrict__ lg, float* __restrict__ out) {
    const int px = blockIdx.x * 256 + threadIdx.x;
    const int y = blockIdx.y;
    const size_t p = (size_t)y * WW + px;
    const float* l = lg + p * 64;
    float v[49];
    float m = -1e30f;
#pragma unroll
    for (int k = 0; k < 49; k++) { v[k] = l[k]; m = fmaxf(m, v[k]); }
    float s = 0.f;
#pragma unroll
    for (int k = 0; k < 49; k++) {
        v[k] = exp2f((v[k] - m) * 1.44269504088896f);
        s += v[k];
    }
    const float inv = 65536.0f / s;
    out[p] = 0.f;
    float run = 0.f;
#pragma unroll
    for (int k = 0; k < 49; k++) {
        run += v[k];
        out[(size_t)(k + 1) * (HH * WW) + p] = run * inv;
    }
}

// ---------------- launcher -------------------------------------------------
extern "C" void kernel_launch(void* const* d_in, const int* in_sizes, int n_in,
                              void* d_out, int out_size, void* d_ws, size_t ws_size,
                              hipStream_t stream) {
    (void)in_sizes; (void)n_in; (void)out_size; (void)ws_size;
    const float* data = (const float*)d_in[0];
    const float* w0   = (const float*)d_in[1];
    const float* b0   = (const float*)d_in[2];
    const float* wres = (const float*)d_in[3];
    const float* bres = (const float*)d_in[4];
    const float* wl   = (const float*)d_in[5];
    const float* bl   = (const float*)d_in[6];
    float* out = (float*)d_out;

    char* ws = (char*)d_ws;
    unsigned short* Xb   = (unsigned short*)ws;                 // 19170432 elems
    unsigned short* Hb   = Xb + XB_E;                           // 19170432
    unsigned short* wpk  = Hb + XB_E;                           // 10*59*144*32 = 2718720
    unsigned short* wpkF = wpk + (size_t)10 * NCH * CPG * 32;   // 59*64*32 = 120832
    float* blp  = (float*)(wpkF + (size_t)NCH * 64 * 32);       // 64
    float* w0p  = blp + 64;                                     // 1728
    float* logits = w0p + 1728;                                 // 131072*64 fp32

    // zero both activation buffers (halos must be 0; ws is poisoned)
    k_zero<<<2048, 256, 0, stream>>>((float*)ws, (2 * XB_E * 2) / 16);

    k_pack_hidden<<<2048, 256, 0, stream>>>(wres, wpk);
    k_pack_final<<<(NCH * 64 * 32 + 255) / 256, 256, 0, stream>>>(wl, wpkF);
    k_pack_small<<<7, 256, 0, stream>>>(w0, bl, w0p, blp);

    k_layer0<<<dim3(8, 256), dim3(64, 6), 0, stream>>>(data, w0p, b0, Xb);

    const size_t LSTRIDE = (size_t)NCH * CPG * 32;   // 271872
    for (int i = 0; i < 5; i++) {
        k_conv<false><<<dim3(4, 128), 768, 0, stream>>>(
            Xb, wpk + (size_t)(2 * i) * LSTRIDE, bres + (2 * i) * CPG, Xb, Hb);
        k_conv<true><<<dim3(4, 128), 768, 0, stream>>>(
            Hb, wpk + (size_t)(2 * i + 1) * LSTRIDE, bres + (2 * i + 1) * CPG, Xb, Xb);
    }

    k_logits<<<dim3(4, 128), 512, 0, stream>>>(Xb, wpkF, blp, logits);
    k_softmax<<<dim3(2, 256), 256, 0, stream>>>(logits, out);
}